// Round 1
// 2818.831 us; speedup vs baseline: 1.4679x; 1.4679x over previous
//
#include <hip/hip_runtime.h>
#include <cstdint>
#include <cstddef>

// ---------------- problem constants ----------------
static constexpr int SEQ  = 2048;
static constexpr int HID  = 2048;
static constexpr int NHQ  = 32;
static constexpr int NHKV = 4;
static constexpr int HD   = 128;
static constexpr int NEXP = 32;
static constexpr int NTOP = 4;
static constexpr int NIMM = 768;
static constexpr float EPS = 1e-6f;

typedef _Float16 f16;
typedef __attribute__((ext_vector_type(8))) _Float16 half8;
typedef __attribute__((ext_vector_type(4))) float f32x4;

static __device__ __forceinline__ f32x4 mfma16(half8 a, half8 b, f32x4 c) {
    return __builtin_amdgcn_mfma_f32_16x16x32_f16(a, b, c, 0, 0, 0);
}

// ---------------- weight transpose+convert: fp32 [K][N] -> f16 [N][K] ----------------
// grid (Kd/64, N/64, batch), block 256. Coalesced fp32 reads; scalar f16 scatter
// stores (write-combined in L2). One pass per launch, amortized across all GEMMs.
__global__ __launch_bounds__(256) void transpose_f16_kernel(
    const float* __restrict__ src, f16* __restrict__ dst, int Kd, int N)
{
    int b = blockIdx.z;
    const float* S = src + (size_t)b * Kd * N;
    f16* D = dst + (size_t)b * Kd * N;
    int k0 = blockIdx.x * 64, n0 = blockIdx.y * 64;
    int t = threadIdx.x;
    int r = t >> 2, cs = (t & 3) * 16;      // r: k-row in tile, cs: n-col segment
    const float* row = S + (size_t)(k0 + r) * N + n0 + cs;
    float4 f0 = *(const float4*)(row);
    float4 f1 = *(const float4*)(row + 4);
    float4 f2 = *(const float4*)(row + 8);
    float4 f3 = *(const float4*)(row + 12);
    float v[16] = {f0.x, f0.y, f0.z, f0.w, f1.x, f1.y, f1.z, f1.w,
                   f2.x, f2.y, f2.z, f2.w, f3.x, f3.y, f3.z, f3.w};
    f16* dcol = D + (size_t)n0 * Kd + k0 + r;
    #pragma unroll
    for (int i = 0; i < 16; i++)
        dcol[(size_t)(cs + i) * Kd] = (f16)v[i];
}

// ---------------- RMSNorm (fp32 in -> f16 out) ----------------
__global__ __launch_bounds__(256) void rmsnorm_f16_kernel(
    const float* __restrict__ x, const float* __restrict__ w, f16* __restrict__ out)
{
    int row = blockIdx.x;
    int tid = threadIdx.x;
    const float* xr = x + (size_t)row * HID;
    float4 a = *(const float4*)(xr + tid * 8);
    float4 b = *(const float4*)(xr + tid * 8 + 4);
    float ss = a.x*a.x + a.y*a.y + a.z*a.z + a.w*a.w
             + b.x*b.x + b.y*b.y + b.z*b.z + b.w*b.w;
    __shared__ float red[4];
    #pragma unroll
    for (int o = 32; o > 0; o >>= 1) ss += __shfl_xor(ss, o);
    if ((tid & 63) == 0) red[tid >> 6] = ss;
    __syncthreads();
    float tot = red[0] + red[1] + red[2] + red[3];
    float sc = rsqrtf(tot / (float)HID + EPS);
    float vals[8] = {a.x, a.y, a.z, a.w, b.x, b.y, b.z, b.w};
    const float* wr = w + tid * 8;
    half8 o;
    #pragma unroll
    for (int i = 0; i < 8; i++) o[i] = (f16)(vals[i] * sc * wr[i]);
    *(half8*)(out + (size_t)row * HID + tid * 8) = o;
}

// ---------------- fast GEMM: C[MxN] = A[MxK](f16,K-major) @ BT[NxK](f16,K-major) ----
// Ch != nullptr: write f16.  else: Cf = acc + resid (fp32).
// Staging is pure uint4 copies for BOTH operands (no conversion, no scalar writes).
__global__ __launch_bounds__(256) void gemm_f16t_kernel(
    const f16* __restrict__ A, const f16* __restrict__ BT,
    f16* __restrict__ Ch, float* __restrict__ Cf, const float* __restrict__ resid,
    int N, int Kd)
{
    __shared__ f16 As[128 * 40];
    __shared__ f16 Bs[128 * 40];
    int tid = threadIdx.x;
    int m0 = blockIdx.y * 128, n0 = blockIdx.x * 128;
    int w = tid >> 6, lane = tid & 63, q4 = lane >> 4, c = lane & 15;
    int wm = (w >> 1) * 64, wn = (w & 1) * 64;
    f32x4 acc[4][4];
    #pragma unroll
    for (int i = 0; i < 4; i++)
        #pragma unroll
        for (int j = 0; j < 4; j++) acc[i][j] = (f32x4){0.f, 0.f, 0.f, 0.f};

    int sr = tid >> 1, sseg = (tid & 1) * 16;
    const f16* Abase = A  + (size_t)(m0 + sr) * Kd + sseg;
    const f16* Bbase = BT + (size_t)(n0 + sr) * Kd + sseg;

    for (int kb = 0; kb < Kd; kb += 32) {
        __syncthreads();
        const uint4* ga = (const uint4*)(Abase + kb);
        uint4 a0 = ga[0], a1 = ga[1];
        const uint4* gb = (const uint4*)(Bbase + kb);
        uint4 b0 = gb[0], b1 = gb[1];
        *(uint4*)&As[sr * 40 + sseg]     = a0;
        *(uint4*)&As[sr * 40 + sseg + 8] = a1;
        *(uint4*)&Bs[sr * 40 + sseg]     = b0;
        *(uint4*)&Bs[sr * 40 + sseg + 8] = b1;
        __syncthreads();
        half8 aF[4], bF[4];
        #pragma unroll
        for (int mt = 0; mt < 4; mt++)
            aF[mt] = *(const half8*)&As[(wm + mt * 16 + c) * 40 + q4 * 8];
        #pragma unroll
        for (int nt = 0; nt < 4; nt++)
            bF[nt] = *(const half8*)&Bs[(wn + nt * 16 + c) * 40 + q4 * 8];
        #pragma unroll
        for (int mt = 0; mt < 4; mt++)
            #pragma unroll
            for (int nt = 0; nt < 4; nt++)
                acc[mt][nt] = mfma16(aF[mt], bF[nt], acc[mt][nt]);
    }
    #pragma unroll
    for (int mt = 0; mt < 4; mt++)
        #pragma unroll
        for (int nt = 0; nt < 4; nt++)
            #pragma unroll
            for (int r = 0; r < 4; r++) {
                int row = m0 + wm + mt * 16 + q4 * 4 + r;
                int col = n0 + wn + nt * 16 + c;
                float v = acc[mt][nt][r];
                if (Ch) Ch[(size_t)row * N + col] = (f16)v;
                else    Cf[(size_t)row * N + col] = v + resid[(size_t)row * N + col];
            }
}

// ---------------- legacy GEMM: C[MxN] = A[MxK](f16) @ B[KxN](fp32) ----------------
// (fallback path when workspace is too small for transposed f16 weights)
__global__ __launch_bounds__(256) void gemm_f16_kernel(
    const f16* __restrict__ A, const float* __restrict__ B,
    f16* __restrict__ Ch, float* __restrict__ Cf, const float* __restrict__ resid,
    int N, int Kd)
{
    __shared__ f16 As[128 * 40];
    __shared__ f16 Bs[128 * 40];
    int tid = threadIdx.x;
    int m0 = blockIdx.y * 128, n0 = blockIdx.x * 128;
    int w = tid >> 6, lane = tid & 63, q4 = lane >> 4, c = lane & 15;
    int wm = (w >> 1) * 64, wn = (w & 1) * 64;
    f32x4 acc[4][4];
    #pragma unroll
    for (int i = 0; i < 4; i++)
        #pragma unroll
        for (int j = 0; j < 4; j++) acc[i][j] = (f32x4){0.f, 0.f, 0.f, 0.f};

    int ar = tid >> 1, aseg = (tid & 1) * 16;
    int bk = tid >> 3, bn = (tid & 7) * 16;

    for (int kb = 0; kb < Kd; kb += 32) {
        __syncthreads();
        {
            const uint4* g = (const uint4*)(A + (size_t)(m0 + ar) * Kd + kb + aseg);
            uint4 u0 = g[0], u1 = g[1];
            *(uint4*)&As[ar * 40 + aseg] = u0;
            *(uint4*)&As[ar * 40 + aseg + 8] = u1;
        }
        {
            const float* g = B + (size_t)(kb + bk) * N + n0 + bn;
            float4 f0 = *(const float4*)(g);
            float4 f1 = *(const float4*)(g + 4);
            float4 f2 = *(const float4*)(g + 8);
            float4 f3 = *(const float4*)(g + 12);
            float vv[16] = {f0.x, f0.y, f0.z, f0.w, f1.x, f1.y, f1.z, f1.w,
                            f2.x, f2.y, f2.z, f2.w, f3.x, f3.y, f3.z, f3.w};
            #pragma unroll
            for (int i = 0; i < 16; i++) Bs[(bn + i) * 40 + bk] = (f16)vv[i];
        }
        __syncthreads();
        half8 aF[4], bF[4];
        #pragma unroll
        for (int mt = 0; mt < 4; mt++)
            aF[mt] = *(const half8*)&As[(wm + mt * 16 + c) * 40 + q4 * 8];
        #pragma unroll
        for (int nt = 0; nt < 4; nt++)
            bF[nt] = *(const half8*)&Bs[(wn + nt * 16 + c) * 40 + q4 * 8];
        #pragma unroll
        for (int mt = 0; mt < 4; mt++)
            #pragma unroll
            for (int nt = 0; nt < 4; nt++)
                acc[mt][nt] = mfma16(aF[mt], bF[nt], acc[mt][nt]);
    }
    #pragma unroll
    for (int mt = 0; mt < 4; mt++)
        #pragma unroll
        for (int nt = 0; nt < 4; nt++)
            #pragma unroll
            for (int r = 0; r < 4; r++) {
                int row = m0 + wm + mt * 16 + q4 * 4 + r;
                int col = n0 + wn + nt * 16 + c;
                float v = acc[mt][nt][r];
                if (Ch) Ch[(size_t)row * N + col] = (f16)v;
                else    Cf[(size_t)row * N + col] = v + resid[(size_t)row * N + col];
            }
}

// ---------------- per-head QK RMSNorm + RoPE (in place, f16) ----------------
__global__ __launch_bounds__(64) void qknorm_rope_kernel(
    f16* __restrict__ qb, f16* __restrict__ kb,
    const float* __restrict__ qn, const float* __restrict__ kn,
    const float* __restrict__ cosp, const float* __restrict__ sinp)
{
    int t = blockIdx.x, y = blockIdx.y, lane = threadIdx.x;
    f16* ptr; const float* w;
    if (y < NHQ) { ptr = qb + (size_t)t * NHQ * HD + y * HD; w = qn; }
    else         { ptr = kb + (size_t)t * NHKV * HD + (y - NHQ) * HD; w = kn; }
    float v0 = (float)ptr[lane], v1 = (float)ptr[lane + 64];
    float ss = v0 * v0 + v1 * v1;
    #pragma unroll
    for (int o = 32; o > 0; o >>= 1) ss += __shfl_xor(ss, o);
    float sc = rsqrtf(ss / (float)HD + EPS);
    float n0 = v0 * sc * w[lane], n1 = v1 * sc * w[lane + 64];
    float c0 = cosp[t * HD + lane],     s0 = sinp[t * HD + lane];
    float c1 = cosp[t * HD + lane + 64], s1 = sinp[t * HD + lane + 64];
    ptr[lane]      = (f16)(n0 * c0 - n1 * s0);
    ptr[lane + 64] = (f16)(n1 * c1 + n0 * s1);
}

// ---------------- causal GQA flash attention ----------------
__global__ __launch_bounds__(256) void attn_kernel(
    const f16* __restrict__ qb, const f16* __restrict__ kbuf,
    const f16* __restrict__ vbuf, f16* __restrict__ ob)
{
    int qt = blockIdx.x, hq = blockIdx.y, kvh = hq >> 3;
    int q0 = qt * 64;
    int tid = threadIdx.x, w = tid >> 6, lane = tid & 63, q4 = lane >> 4, c = lane & 15;
    __shared__ f16 Qs[64 * 136];
    __shared__ f16 Ks[64 * 136];
    __shared__ f16 Vt[128 * 72];
    __shared__ f16 Ps[64 * 72];
    {
        int r = tid >> 2, seg = (tid & 3) * 32;
        const uint4* g = (const uint4*)(qb + (size_t)(q0 + r) * (NHQ * HD) + hq * HD + seg);
        uint4* d = (uint4*)&Qs[r * 136 + seg];
        d[0] = g[0]; d[1] = g[1]; d[2] = g[2]; d[3] = g[3];
    }
    float mi[4] = {-1e30f, -1e30f, -1e30f, -1e30f};
    float li[4] = {0.f, 0.f, 0.f, 0.f};
    f32x4 O[8];
    #pragma unroll
    for (int i = 0; i < 8; i++) O[i] = (f32x4){0.f, 0.f, 0.f, 0.f};
    const float scale = 0.08838834764831845f;

    for (int kt = 0; kt <= qt; kt++) {
        __syncthreads();
        {
            int r = tid >> 2, seg = (tid & 3) * 32;
            const uint4* g = (const uint4*)(kbuf + (size_t)(kt * 64 + r) * (NHKV * HD) + kvh * HD + seg);
            uint4* d = (uint4*)&Ks[r * 136 + seg];
            d[0] = g[0]; d[1] = g[1]; d[2] = g[2]; d[3] = g[3];
            const uint4* gv = (const uint4*)(vbuf + (size_t)(kt * 64 + r) * (NHKV * HD) + kvh * HD + seg);
            union { uint4 u; f16 h[8]; } t0, t1, t2, t3;
            t0.u = gv[0]; t1.u = gv[1]; t2.u = gv[2]; t3.u = gv[3];
            #pragma unroll
            for (int i = 0; i < 8; i++) {
                Vt[(seg + i) * 72 + r]      = t0.h[i];
                Vt[(seg + 8 + i) * 72 + r]  = t1.h[i];
                Vt[(seg + 16 + i) * 72 + r] = t2.h[i];
                Vt[(seg + 24 + i) * 72 + r] = t3.h[i];
            }
        }
        __syncthreads();
        f32x4 s[4];
        #pragma unroll
        for (int nt = 0; nt < 4; nt++) s[nt] = (f32x4){0.f, 0.f, 0.f, 0.f};
        #pragma unroll
        for (int kk = 0; kk < 4; kk++) {
            half8 a = *(const half8*)&Qs[(w * 16 + c) * 136 + kk * 32 + q4 * 8];
            #pragma unroll
            for (int nt = 0; nt < 4; nt++) {
                half8 b = *(const half8*)&Ks[(nt * 16 + c) * 136 + kk * 32 + q4 * 8];
                s[nt] = mfma16(a, b, s[nt]);
            }
        }
        bool diag = (kt == qt);
        float rmax[4] = {-1e30f, -1e30f, -1e30f, -1e30f};
        #pragma unroll
        for (int nt = 0; nt < 4; nt++)
            #pragma unroll
            for (int r = 0; r < 4; r++) {
                float v = s[nt][r] * scale;
                if (diag && (nt * 16 + c) > (w * 16 + q4 * 4 + r)) v = -1e30f;
                s[nt][r] = v;
                rmax[r] = fmaxf(rmax[r], v);
            }
        #pragma unroll
        for (int o = 1; o < 16; o <<= 1)
            #pragma unroll
            for (int r = 0; r < 4; r++) rmax[r] = fmaxf(rmax[r], __shfl_xor(rmax[r], o));
        float alpha[4];
        #pragma unroll
        for (int r = 0; r < 4; r++) {
            float mn = fmaxf(mi[r], rmax[r]);
            alpha[r] = expf(mi[r] - mn);
            mi[r] = mn;
        }
        float rs[4] = {0.f, 0.f, 0.f, 0.f};
        #pragma unroll
        for (int nt = 0; nt < 4; nt++)
            #pragma unroll
            for (int r = 0; r < 4; r++) {
                float p = expf(s[nt][r] - mi[r]);
                s[nt][r] = p;
                rs[r] += p;
            }
        #pragma unroll
        for (int o = 1; o < 16; o <<= 1)
            #pragma unroll
            for (int r = 0; r < 4; r++) rs[r] += __shfl_xor(rs[r], o);
        #pragma unroll
        for (int r = 0; r < 4; r++) li[r] = li[r] * alpha[r] + rs[r];
        #pragma unroll
        for (int nt = 0; nt < 8; nt++)
            #pragma unroll
            for (int r = 0; r < 4; r++) O[nt][r] *= alpha[r];
        #pragma unroll
        for (int nt = 0; nt < 4; nt++)
            #pragma unroll
            for (int r = 0; r < 4; r++)
                Ps[(w * 16 + q4 * 4 + r) * 72 + nt * 16 + c] = (f16)s[nt][r];
        __syncthreads();
        #pragma unroll
        for (int kk = 0; kk < 2; kk++) {
            half8 a = *(const half8*)&Ps[(w * 16 + c) * 72 + kk * 32 + q4 * 8];
            #pragma unroll
            for (int nt = 0; nt < 8; nt++) {
                half8 b = *(const half8*)&Vt[(nt * 16 + c) * 72 + kk * 32 + q4 * 8];
                O[nt] = mfma16(a, b, O[nt]);
            }
        }
    }
    #pragma unroll
    for (int r = 0; r < 4; r++) {
        float inv = 1.f / li[r];
        int row = q0 + w * 16 + q4 * 4 + r;
        #pragma unroll
        for (int nt = 0; nt < 8; nt++)
            ob[(size_t)row * (NHQ * HD) + hq * HD + nt * 16 + c] = (f16)(O[nt][r] * inv);
    }
}

// ---------------- gate: fp32 rmsnorm + logits + softmax + top-4 + routing ----------------
__global__ __launch_bounds__(256) void gate_kernel(
    const float* __restrict__ x2, const float* __restrict__ pw,
    const float* __restrict__ gw, float* __restrict__ topw,
    int* __restrict__ counts, int* __restrict__ bucket)
{
    int token = blockIdx.x, tid = threadIdx.x;
    const float* xr = x2 + (size_t)token * HID;
    float4 a = *(const float4*)(xr + tid * 8);
    float4 b = *(const float4*)(xr + tid * 8 + 4);
    float ss = a.x*a.x + a.y*a.y + a.z*a.z + a.w*a.w
             + b.x*b.x + b.y*b.y + b.z*b.z + b.w*b.w;
    __shared__ float red[4];
    __shared__ float lg[NEXP];
    #pragma unroll
    for (int o = 32; o > 0; o >>= 1) ss += __shfl_xor(ss, o);
    if ((tid & 63) == 0) red[tid >> 6] = ss;
    __syncthreads();
    float tot = red[0] + red[1] + red[2] + red[3];
    float inv = rsqrtf(tot / (float)HID + EPS);
    int e = tid >> 3, sub = tid & 7;
    const float* ge = gw + (size_t)e * HID;
    float acc = 0.f;
    for (int i = sub; i < HID; i += 8) acc += xr[i] * pw[i] * ge[i];
    acc *= inv;
    acc += __shfl_xor(acc, 1);
    acc += __shfl_xor(acc, 2);
    acc += __shfl_xor(acc, 4);
    if (sub == 0) lg[e] = acc;
    __syncthreads();
    if (tid == 0) {
        float m = lg[0];
        for (int i = 1; i < NEXP; i++) m = fmaxf(m, lg[i]);
        float ex[NEXP];
        for (int i = 0; i < NEXP; i++) ex[i] = expf(lg[i] - m);
        bool used[NEXP];
        for (int i = 0; i < NEXP; i++) used[i] = false;
        int ids[NTOP]; float vals[NTOP]; float sum4 = 0.f;
        for (int j = 0; j < NTOP; j++) {
            int best = -1; float bv = -1.f;
            for (int i = 0; i < NEXP; i++)
                if (!used[i] && ex[i] > bv) { bv = ex[i]; best = i; }
            used[best] = true; ids[j] = best; vals[j] = bv; sum4 += bv;
        }
        for (int j = 0; j < NTOP; j++) {
            topw[token * NTOP + j] = vals[j] / sum4;
            int pos = atomicAdd(&counts[ids[j]], 1);
            bucket[ids[j] * SEQ + pos] = token * NTOP + j;
        }
    }
}

// ---------------- MoE pass A (fast): act = silu(x@wg) * (x@wu), wgT/wuT f16 [e][I][H] ----
__global__ __launch_bounds__(256) void moe_gu_t_kernel(
    const f16* __restrict__ h2, const f16* __restrict__ wgT,
    const f16* __restrict__ wuT, const int* __restrict__ counts,
    const int* __restrict__ bucket, f16* __restrict__ act)
{
    int e = blockIdx.y, mt64 = blockIdx.x, nb = blockIdx.z;
    int cnt = counts[e];
    if (mt64 * 64 >= cnt) return;
    __shared__ f16 As[64 * 40];
    __shared__ f16 Bg[128 * 40];
    __shared__ f16 Bu[128 * 40];
    __shared__ int pair_s[64];
    int tid = threadIdx.x;
    if (tid < 64) {
        int r = mt64 * 64 + tid;
        pair_s[tid] = (r < cnt) ? bucket[e * SEQ + r] : -1;
    }
    __syncthreads();
    int w = tid >> 6, lane = tid & 63, q4 = lane >> 4, c = lane & 15;
    f32x4 ag[8], au[8];
    #pragma unroll
    for (int i = 0; i < 8; i++) { ag[i] = (f32x4){0.f,0.f,0.f,0.f}; au[i] = (f32x4){0.f,0.f,0.f,0.f}; }
    int ar = tid >> 2, aseg = (tid & 3) * 8;
    int br = tid >> 1, bseg = (tid & 1) * 16;
    int n0 = nb * 128;
    const f16* gBase = wgT + (size_t)e * NIMM * HID + (size_t)(n0 + br) * HID + bseg;
    const f16* uBase = wuT + (size_t)e * NIMM * HID + (size_t)(n0 + br) * HID + bseg;
    int pA = pair_s[ar];
    const f16* aBase = (pA >= 0) ? (h2 + (size_t)(pA >> 2) * HID + aseg) : nullptr;
    for (int kb = 0; kb < HID; kb += 32) {
        __syncthreads();
        {
            uint4 u = {0, 0, 0, 0};
            if (aBase) u = *(const uint4*)(aBase + kb);
            *(uint4*)&As[ar * 40 + aseg] = u;
        }
        {
            const uint4* gg = (const uint4*)(gBase + kb);
            uint4 g0 = gg[0], g1 = gg[1];
            const uint4* gu = (const uint4*)(uBase + kb);
            uint4 u0 = gu[0], u1 = gu[1];
            *(uint4*)&Bg[br * 40 + bseg]     = g0;
            *(uint4*)&Bg[br * 40 + bseg + 8] = g1;
            *(uint4*)&Bu[br * 40 + bseg]     = u0;
            *(uint4*)&Bu[br * 40 + bseg + 8] = u1;
        }
        __syncthreads();
        half8 aF = *(const half8*)&As[(w * 16 + c) * 40 + q4 * 8];
        #pragma unroll
        for (int nt = 0; nt < 8; nt++) {
            half8 bg = *(const half8*)&Bg[(nt * 16 + c) * 40 + q4 * 8];
            ag[nt] = mfma16(aF, bg, ag[nt]);
            half8 bu = *(const half8*)&Bu[(nt * 16 + c) * 40 + q4 * 8];
            au[nt] = mfma16(aF, bu, au[nt]);
        }
    }
    #pragma unroll
    for (int nt = 0; nt < 8; nt++)
        #pragma unroll
        for (int r = 0; r < 4; r++) {
            int rl = w * 16 + q4 * 4 + r;
            int p = pair_s[rl];
            if (p >= 0) {
                float g = ag[nt][r], u = au[nt][r];
                float sv = g / (1.f + expf(-g)) * u;
                act[(size_t)p * NIMM + n0 + nt * 16 + c] = (f16)sv;
            }
        }
}

// ---------------- MoE pass B (fast): out[token] += w * (act @ wd[e]), wdT f16 [e][H][I] ----
__global__ __launch_bounds__(256) void moe_d_t_kernel(
    const f16* __restrict__ act, const f16* __restrict__ wdT,
    const int* __restrict__ counts, const int* __restrict__ bucket,
    const float* __restrict__ topw, float* __restrict__ out)
{
    int e = blockIdx.y, mt64 = blockIdx.x, nb = blockIdx.z;
    int cnt = counts[e];
    if (mt64 * 64 >= cnt) return;
    __shared__ f16 As[64 * 40];
    __shared__ f16 Bs[128 * 40];
    __shared__ int pair_s[64];
    int tid = threadIdx.x;
    if (tid < 64) {
        int r = mt64 * 64 + tid;
        pair_s[tid] = (r < cnt) ? bucket[e * SEQ + r] : -1;
    }
    __syncthreads();
    int w = tid >> 6, lane = tid & 63, q4 = lane >> 4, c = lane & 15;
    f32x4 acc[8];
    #pragma unroll
    for (int i = 0; i < 8; i++) acc[i] = (f32x4){0.f, 0.f, 0.f, 0.f};
    int ar = tid >> 2, aseg = (tid & 3) * 8;
    int br = tid >> 1, bseg = (tid & 1) * 16;
    int n0 = nb * 128;
    const f16* Bbase = wdT + (size_t)e * HID * NIMM + (size_t)(n0 + br) * NIMM + bseg;
    int pA = pair_s[ar];
    const f16* aBase = (pA >= 0) ? (act + (size_t)pA * NIMM + aseg) : nullptr;
    for (int kb = 0; kb < NIMM; kb += 32) {
        __syncthreads();
        {
            uint4 u = {0, 0, 0, 0};
            if (aBase) u = *(const uint4*)(aBase + kb);
            *(uint4*)&As[ar * 40 + aseg] = u;
        }
        {
            const uint4* gb = (const uint4*)(Bbase + kb);
            uint4 b0 = gb[0], b1 = gb[1];
            *(uint4*)&Bs[br * 40 + bseg]     = b0;
            *(uint4*)&Bs[br * 40 + bseg + 8] = b1;
        }
        __syncthreads();
        half8 aF = *(const half8*)&As[(w * 16 + c) * 40 + q4 * 8];
        #pragma unroll
        for (int nt = 0; nt < 8; nt++) {
            half8 b = *(const half8*)&Bs[(nt * 16 + c) * 40 + q4 * 8];
            acc[nt] = mfma16(aF, b, acc[nt]);
        }
    }
    #pragma unroll
    for (int nt = 0; nt < 8; nt++)
        #pragma unroll
        for (int r = 0; r < 4; r++) {
            int rl = w * 16 + q4 * 4 + r;
            int p = pair_s[rl];
            if (p >= 0) {
                float wgt = topw[p];
                atomicAdd(&out[(size_t)(p >> 2) * HID + n0 + nt * 16 + c],
                          acc[nt][r] * wgt);
            }
        }
}

// ---------------- legacy MoE kernels (fp32-weight fallback) ----------------
__global__ __launch_bounds__(256) void moe_gu_kernel(
    const f16* __restrict__ h2, const float* __restrict__ wg,
    const float* __restrict__ wu, const int* __restrict__ counts,
    const int* __restrict__ bucket, f16* __restrict__ act)
{
    int e = blockIdx.y, mt64 = blockIdx.x, nb = blockIdx.z;
    int cnt = counts[e];
    if (mt64 * 64 >= cnt) return;
    __shared__ f16 As[64 * 40];
    __shared__ f16 Bg[128 * 40];
    __shared__ f16 Bu[128 * 40];
    __shared__ int pair_s[64];
    int tid = threadIdx.x;
    if (tid < 64) {
        int r = mt64 * 64 + tid;
        pair_s[tid] = (r < cnt) ? bucket[e * SEQ + r] : -1;
    }
    __syncthreads();
    int w = tid >> 6, lane = tid & 63, q4 = lane >> 4, c = lane & 15;
    f32x4 ag[8], au[8];
    #pragma unroll
    for (int i = 0; i < 8; i++) { ag[i] = (f32x4){0.f,0.f,0.f,0.f}; au[i] = (f32x4){0.f,0.f,0.f,0.f}; }
    int ar = tid >> 2, aseg = (tid & 3) * 8;
    int bk = tid >> 3, bn = (tid & 7) * 16;
    const float* gB = wg + (size_t)e * HID * NIMM;
    const float* uB = wu + (size_t)e * HID * NIMM;
    int n0 = nb * 128;
    int pA = pair_s[ar];
    for (int kb = 0; kb < HID; kb += 32) {
        __syncthreads();
        {
            uint4 u = {0, 0, 0, 0};
            if (pA >= 0) u = *(const uint4*)(h2 + (size_t)(pA >> 2) * HID + kb + aseg);
            *(uint4*)&As[ar * 40 + aseg] = u;
        }
        {
            const float* g0 = gB + (size_t)(kb + bk) * NIMM + n0 + bn;
            float4 f0 = *(const float4*)(g0);
            float4 f1 = *(const float4*)(g0 + 4);
            float4 f2 = *(const float4*)(g0 + 8);
            float4 f3 = *(const float4*)(g0 + 12);
            float vv[16] = {f0.x, f0.y, f0.z, f0.w, f1.x, f1.y, f1.z, f1.w,
                            f2.x, f2.y, f2.z, f2.w, f3.x, f3.y, f3.z, f3.w};
            #pragma unroll
            for (int i = 0; i < 16; i++) Bg[(bn + i) * 40 + bk] = (f16)vv[i];
            const float* g1 = uB + (size_t)(kb + bk) * NIMM + n0 + bn;
            float4 u0 = *(const float4*)(g1);
            float4 u1 = *(const float4*)(g1 + 4);
            float4 u2 = *(const float4*)(g1 + 8);
            float4 u3 = *(const float4*)(g1 + 12);
            float uu[16] = {u0.x, u0.y, u0.z, u0.w, u1.x, u1.y, u1.z, u1.w,
                            u2.x, u2.y, u2.z, u2.w, u3.x, u3.y, u3.z, u3.w};
            #pragma unroll
            for (int i = 0; i < 16; i++) Bu[(bn + i) * 40 + bk] = (f16)uu[i];
        }
        __syncthreads();
        half8 aF = *(const half8*)&As[(w * 16 + c) * 40 + q4 * 8];
        #pragma unroll
        for (int nt = 0; nt < 8; nt++) {
            half8 bg = *(const half8*)&Bg[(nt * 16 + c) * 40 + q4 * 8];
            ag[nt] = mfma16(aF, bg, ag[nt]);
            half8 bu = *(const half8*)&Bu[(nt * 16 + c) * 40 + q4 * 8];
            au[nt] = mfma16(aF, bu, au[nt]);
        }
    }
    #pragma unroll
    for (int nt = 0; nt < 8; nt++)
        #pragma unroll
        for (int r = 0; r < 4; r++) {
            int rl = w * 16 + q4 * 4 + r;
            int p = pair_s[rl];
            if (p >= 0) {
                float g = ag[nt][r], u = au[nt][r];
                float sv = g / (1.f + expf(-g)) * u;
                act[(size_t)p * NIMM + n0 + nt * 16 + c] = (f16)sv;
            }
        }
}

__global__ __launch_bounds__(256) void moe_d_kernel(
    const f16* __restrict__ act, const float* __restrict__ wd,
    const int* __restrict__ counts, const int* __restrict__ bucket,
    const float* __restrict__ topw, float* __restrict__ out)
{
    int e = blockIdx.y, mt64 = blockIdx.x, nb = blockIdx.z;
    int cnt = counts[e];
    if (mt64 * 64 >= cnt) return;
    __shared__ f16 As[64 * 40];
    __shared__ f16 Bs[128 * 40];
    __shared__ int pair_s[64];
    int tid = threadIdx.x;
    if (tid < 64) {
        int r = mt64 * 64 + tid;
        pair_s[tid] = (r < cnt) ? bucket[e * SEQ + r] : -1;
    }
    __syncthreads();
    int w = tid >> 6, lane = tid & 63, q4 = lane >> 4, c = lane & 15;
    f32x4 acc[8];
    #pragma unroll
    for (int i = 0; i < 8; i++) acc[i] = (f32x4){0.f, 0.f, 0.f, 0.f};
    int ar = tid >> 2, aseg = (tid & 3) * 8;
    int bk = tid >> 3, bn = (tid & 7) * 16;
    const float* B = wd + (size_t)e * NIMM * HID;
    int n0 = nb * 128;
    int pA = pair_s[ar];
    for (int kb = 0; kb < NIMM; kb += 32) {
        __syncthreads();
        {
            uint4 u = {0, 0, 0, 0};
            if (pA >= 0) u = *(const uint4*)(act + (size_t)pA * NIMM + kb + aseg);
            *(uint4*)&As[ar * 40 + aseg] = u;
        }
        {
            const float* g = B + (size_t)(kb + bk) * HID + n0 + bn;
            float4 f0 = *(const float4*)(g);
            float4 f1 = *(const float4*)(g + 4);
            float4 f2 = *(const float4*)(g + 8);
            float4 f3 = *(const float4*)(g + 12);
            float vv[16] = {f0.x, f0.y, f0.z, f0.w, f1.x, f1.y, f1.z, f1.w,
                            f2.x, f2.y, f2.z, f2.w, f3.x, f3.y, f3.z, f3.w};
            #pragma unroll
            for (int i = 0; i < 16; i++) Bs[(bn + i) * 40 + bk] = (f16)vv[i];
        }
        __syncthreads();
        half8 aF = *(const half8*)&As[(w * 16 + c) * 40 + q4 * 8];
        #pragma unroll
        for (int nt = 0; nt < 8; nt++) {
            half8 b = *(const half8*)&Bs[(nt * 16 + c) * 40 + q4 * 8];
            acc[nt] = mfma16(aF, b, acc[nt]);
        }
    }
    #pragma unroll
    for (int nt = 0; nt < 8; nt++)
        #pragma unroll
        for (int r = 0; r < 4; r++) {
            int rl = w * 16 + q4 * 4 + r;
            int p = pair_s[rl];
            if (p >= 0) {
                float wgt = topw[p];
                atomicAdd(&out[(size_t)(p >> 2) * HID + n0 + nt * 16 + c],
                          acc[nt][r] * wgt);
            }
        }
}

// ---------------- launch ----------------
extern "C" void kernel_launch(void* const* d_in, const int* in_sizes, int n_in,
                              void* d_out, int out_size, void* d_ws, size_t ws_size,
                              hipStream_t stream)
{
    (void)in_sizes; (void)n_in; (void)out_size;
    const float* x       = (const float*)d_in[0];
    const float* cosp    = (const float*)d_in[1];
    const float* sinp    = (const float*)d_in[2];
    const float* in_ln   = (const float*)d_in[3];
    const float* post_ln = (const float*)d_in[4];
    const float* qn      = (const float*)d_in[5];
    const float* kn      = (const float*)d_in[6];
    const float* wq      = (const float*)d_in[7];
    const float* wk      = (const float*)d_in[8];
    const float* wv      = (const float*)d_in[9];
    const float* wo      = (const float*)d_in[10];
    const float* gw      = (const float*)d_in[11];
    const float* wg      = (const float*)d_in[12];
    const float* wu      = (const float*)d_in[13];
    const float* wd      = (const float*)d_in[14];
    float* out = (float*)d_out;

    char* ws = (char*)d_ws;
    auto alloc = [&](size_t bytes) { char* p = ws; ws += bytes; return p; };

    f16* h_h    = (f16*)alloc((size_t)SEQ * HID * 2);
    f16* q_h    = (f16*)alloc((size_t)SEQ * NHQ * HD * 2);
    f16* k_h    = (f16*)alloc((size_t)SEQ * NHKV * HD * 2);
    f16* v_h    = (f16*)alloc((size_t)SEQ * NHKV * HD * 2);
    f16* attn_h = (f16*)alloc((size_t)SEQ * NHQ * HD * 2);
    f16* h2_h   = (f16*)alloc((size_t)SEQ * HID * 2);
    f16* act    = (f16*)alloc((size_t)SEQ * NTOP * NIMM * 2);
    float* topw = (float*)alloc((size_t)SEQ * NTOP * 4);
    int* counts = (int*)alloc(128);
    int* bucket = (int*)alloc((size_t)NEXP * SEQ * 4);

    // transposed-f16 weight cache (fast path) — ~324 MB on top of ~64 MB base
    const size_t SZ_WQT = (size_t)(NHQ * HD) * HID * 2;
    const size_t SZ_WKT = (size_t)(NHKV * HD) * HID * 2;
    const size_t SZ_WOT = (size_t)HID * (NHQ * HD) * 2;
    const size_t SZ_WGT = (size_t)NEXP * NIMM * HID * 2;
    const size_t SZ_WDT = (size_t)NEXP * HID * NIMM * 2;
    size_t base_used = (size_t)(ws - (char*)d_ws);
    size_t need = base_used + SZ_WQT + 2 * SZ_WKT + SZ_WOT + 2 * SZ_WGT + SZ_WDT;
    bool fast = ws_size >= need;

    // 1. input RMSNorm
    rmsnorm_f16_kernel<<<SEQ, 256, 0, stream>>>(x, in_ln, h_h);

    if (fast) {
        f16* wqT = (f16*)alloc(SZ_WQT);
        f16* wkT = (f16*)alloc(SZ_WKT);
        f16* wvT = (f16*)alloc(SZ_WKT);
        f16* woT = (f16*)alloc(SZ_WOT);
        f16* wgT = (f16*)alloc(SZ_WGT);
        f16* wuT = (f16*)alloc(SZ_WGT);
        f16* wdT = (f16*)alloc(SZ_WDT);

        // 0. weight transpose+convert (once per launch)
        transpose_f16_kernel<<<dim3(HID / 64, NHQ * HD / 64, 1), 256, 0, stream>>>(
            wq, wqT, HID, NHQ * HD);
        transpose_f16_kernel<<<dim3(HID / 64, NHKV * HD / 64, 1), 256, 0, stream>>>(
            wk, wkT, HID, NHKV * HD);
        transpose_f16_kernel<<<dim3(HID / 64, NHKV * HD / 64, 1), 256, 0, stream>>>(
            wv, wvT, HID, NHKV * HD);
        transpose_f16_kernel<<<dim3(NHQ * HD / 64, HID / 64, 1), 256, 0, stream>>>(
            wo, woT, NHQ * HD, HID);
        transpose_f16_kernel<<<dim3(HID / 64, NIMM / 64, NEXP), 256, 0, stream>>>(
            wg, wgT, HID, NIMM);
        transpose_f16_kernel<<<dim3(HID / 64, NIMM / 64, NEXP), 256, 0, stream>>>(
            wu, wuT, HID, NIMM);
        transpose_f16_kernel<<<dim3(NIMM / 64, HID / 64, NEXP), 256, 0, stream>>>(
            wd, wdT, NIMM, HID);

        // 2. QKV projections
        gemm_f16t_kernel<<<dim3(NHQ * HD / 128, SEQ / 128), 256, 0, stream>>>(
            h_h, wqT, q_h, nullptr, nullptr, NHQ * HD, HID);
        gemm_f16t_kernel<<<dim3(NHKV * HD / 128, SEQ / 128), 256, 0, stream>>>(
            h_h, wkT, k_h, nullptr, nullptr, NHKV * HD, HID);
        gemm_f16t_kernel<<<dim3(NHKV * HD / 128, SEQ / 128), 256, 0, stream>>>(
            h_h, wvT, v_h, nullptr, nullptr, NHKV * HD, HID);
        // 3. QK norm + RoPE
        qknorm_rope_kernel<<<dim3(SEQ, NHQ + NHKV), 64, 0, stream>>>(
            q_h, k_h, qn, kn, cosp, sinp);
        // 4. attention
        attn_kernel<<<dim3(SEQ / 64, NHQ), 256, 0, stream>>>(q_h, k_h, v_h, attn_h);
        // 5. Wo GEMM + residual -> out holds x2
        gemm_f16t_kernel<<<dim3(HID / 128, SEQ / 128), 256, 0, stream>>>(
            attn_h, woT, nullptr, out, x, HID, NHQ * HD);
        // 6. post RMSNorm
        rmsnorm_f16_kernel<<<SEQ, 256, 0, stream>>>(out, post_ln, h2_h);
        // 7. routing
        hipMemsetAsync(counts, 0, NEXP * sizeof(int), stream);
        gate_kernel<<<SEQ, 256, 0, stream>>>(out, post_ln, gw, topw, counts, bucket);
        // 8. MoE
        moe_gu_t_kernel<<<dim3(SEQ / 64, NEXP, NIMM / 128), 256, 0, stream>>>(
            h2_h, wgT, wuT, counts, bucket, act);
        moe_d_t_kernel<<<dim3(SEQ / 64, NEXP, HID / 128), 256, 0, stream>>>(
            act, wdT, counts, bucket, topw, out);
    } else {
        // legacy fallback (workspace too small for f16 weight cache)
        gemm_f16_kernel<<<dim3(NHQ * HD / 128, SEQ / 128), 256, 0, stream>>>(
            h_h, wq, q_h, nullptr, nullptr, NHQ * HD, HID);
        gemm_f16_kernel<<<dim3(NHKV * HD / 128, SEQ / 128), 256, 0, stream>>>(
            h_h, wk, k_h, nullptr, nullptr, NHKV * HD, HID);
        gemm_f16_kernel<<<dim3(NHKV * HD / 128, SEQ / 128), 256, 0, stream>>>(
            h_h, wv, v_h, nullptr, nullptr, NHKV * HD, HID);
        qknorm_rope_kernel<<<dim3(SEQ, NHQ + NHKV), 64, 0, stream>>>(
            q_h, k_h, qn, kn, cosp, sinp);
        attn_kernel<<<dim3(SEQ / 64, NHQ), 256, 0, stream>>>(q_h, k_h, v_h, attn_h);
        gemm_f16_kernel<<<dim3(HID / 128, SEQ / 128), 256, 0, stream>>>(
            attn_h, wo, nullptr, out, x, HID, NHQ * HD);
        rmsnorm_f16_kernel<<<SEQ, 256, 0, stream>>>(out, post_ln, h2_h);
        hipMemsetAsync(counts, 0, NEXP * sizeof(int), stream);
        gate_kernel<<<SEQ, 256, 0, stream>>>(out, post_ln, gw, topw, counts, bucket);
        moe_gu_kernel<<<dim3(SEQ / 64, NEXP, NIMM / 128), 256, 0, stream>>>(
            h2_h, wg, wu, counts, bucket, act);
        moe_d_kernel<<<dim3(SEQ / 64, NEXP, HID / 128), 256, 0, stream>>>(
            act, wd, counts, bucket, topw, out);
    }
}

// Round 2
// 1644.760 us; speedup vs baseline: 2.5157x; 1.7138x over previous
//
#include <hip/hip_runtime.h>
#include <cstdint>
#include <cstddef>

// ---------------- problem constants ----------------
static constexpr int SEQ  = 2048;
static constexpr int HID  = 2048;
static constexpr int NHQ  = 32;
static constexpr int NHKV = 4;
static constexpr int HD   = 128;
static constexpr int NEXP = 32;
static constexpr int NTOP = 4;
static constexpr int NIMM = 768;
static constexpr float EPS = 1e-6f;

typedef _Float16 f16;
typedef __attribute__((ext_vector_type(8))) _Float16 half8;
typedef __attribute__((ext_vector_type(4))) float f32x4;

static __device__ __forceinline__ f32x4 mfma16(half8 a, half8 b, f32x4 c) {
    return __builtin_amdgcn_mfma_f32_16x16x32_f16(a, b, c, 0, 0, 0);
}

// ---------------- weight transpose+convert: fp32 [K][N] -> f16 [N][K] ----------------
__global__ __launch_bounds__(256) void transpose_f16_kernel(
    const float* __restrict__ src, f16* __restrict__ dst, int Kd, int N)
{
    int b = blockIdx.z;
    const float* S = src + (size_t)b * Kd * N;
    f16* D = dst + (size_t)b * Kd * N;
    int k0 = blockIdx.x * 64, n0 = blockIdx.y * 64;
    int t = threadIdx.x;
    int r = t >> 2, cs = (t & 3) * 16;
    const float* row = S + (size_t)(k0 + r) * N + n0 + cs;
    float4 f0 = *(const float4*)(row);
    float4 f1 = *(const float4*)(row + 4);
    float4 f2 = *(const float4*)(row + 8);
    float4 f3 = *(const float4*)(row + 12);
    float v[16] = {f0.x, f0.y, f0.z, f0.w, f1.x, f1.y, f1.z, f1.w,
                   f2.x, f2.y, f2.z, f2.w, f3.x, f3.y, f3.z, f3.w};
    f16* dcol = D + (size_t)n0 * Kd + k0 + r;
    #pragma unroll
    for (int i = 0; i < 16; i++)
        dcol[(size_t)(cs + i) * Kd] = (f16)v[i];
}

// ---------------- RMSNorm (fp32 in -> f16 out) ----------------
__global__ __launch_bounds__(256) void rmsnorm_f16_kernel(
    const float* __restrict__ x, const float* __restrict__ w, f16* __restrict__ out)
{
    int row = blockIdx.x;
    int tid = threadIdx.x;
    const float* xr = x + (size_t)row * HID;
    float4 a = *(const float4*)(xr + tid * 8);
    float4 b = *(const float4*)(xr + tid * 8 + 4);
    float ss = a.x*a.x + a.y*a.y + a.z*a.z + a.w*a.w
             + b.x*b.x + b.y*b.y + b.z*b.z + b.w*b.w;
    __shared__ float red[4];
    #pragma unroll
    for (int o = 32; o > 0; o >>= 1) ss += __shfl_xor(ss, o);
    if ((tid & 63) == 0) red[tid >> 6] = ss;
    __syncthreads();
    float tot = red[0] + red[1] + red[2] + red[3];
    float sc = rsqrtf(tot / (float)HID + EPS);
    float vals[8] = {a.x, a.y, a.z, a.w, b.x, b.y, b.z, b.w};
    const float* wr = w + tid * 8;
    half8 o;
    #pragma unroll
    for (int i = 0; i < 8; i++) o[i] = (f16)(vals[i] * sc * wr[i]);
    *(half8*)(out + (size_t)row * HID + tid * 8) = o;
}

// ---------------- fast GEMM (pipelined): C = A[MxK](f16) @ BT[NxK](f16) ----------
// Double-buffered LDS, register prefetch, one barrier per K-step.
__global__ __launch_bounds__(256) void gemm_f16t_kernel(
    const f16* __restrict__ A, const f16* __restrict__ BT,
    f16* __restrict__ Ch, float* __restrict__ Cf, const float* __restrict__ resid,
    int N, int Kd)
{
    __shared__ f16 As[2][128 * 40];
    __shared__ f16 Bs[2][128 * 40];
    int tid = threadIdx.x;
    int m0 = blockIdx.y * 128, n0 = blockIdx.x * 128;
    int w = tid >> 6, lane = tid & 63, q4 = lane >> 4, c = lane & 15;
    int wm = (w >> 1) * 64, wn = (w & 1) * 64;
    f32x4 acc[4][4];
    #pragma unroll
    for (int i = 0; i < 4; i++)
        #pragma unroll
        for (int j = 0; j < 4; j++) acc[i][j] = (f32x4){0.f, 0.f, 0.f, 0.f};

    int sr = tid >> 1, sseg = (tid & 1) * 16;
    const f16* Abase = A  + (size_t)(m0 + sr) * Kd + sseg;
    const f16* Bbase = BT + (size_t)(n0 + sr) * Kd + sseg;

    uint4 ra0, ra1, rb0, rb1;
    auto LOADT = [&](int t) {
        const uint4* ga = (const uint4*)(Abase + t * 32);
        ra0 = ga[0]; ra1 = ga[1];
        const uint4* gb = (const uint4*)(Bbase + t * 32);
        rb0 = gb[0]; rb1 = gb[1];
    };
    auto WRITET = [&](int buf) {
        *(uint4*)&As[buf][sr * 40 + sseg]     = ra0;
        *(uint4*)&As[buf][sr * 40 + sseg + 8] = ra1;
        *(uint4*)&Bs[buf][sr * 40 + sseg]     = rb0;
        *(uint4*)&Bs[buf][sr * 40 + sseg + 8] = rb1;
    };
    auto COMPUTE = [&](int buf) {
        half8 aF[4], bF[4];
        #pragma unroll
        for (int mt = 0; mt < 4; mt++)
            aF[mt] = *(const half8*)&As[buf][(wm + mt * 16 + c) * 40 + q4 * 8];
        #pragma unroll
        for (int nt = 0; nt < 4; nt++)
            bF[nt] = *(const half8*)&Bs[buf][(wn + nt * 16 + c) * 40 + q4 * 8];
        #pragma unroll
        for (int mt = 0; mt < 4; mt++)
            #pragma unroll
            for (int nt = 0; nt < 4; nt++)
                acc[mt][nt] = mfma16(aF[mt], bF[nt], acc[mt][nt]);
    };

    int NT = Kd >> 5;
    LOADT(0); WRITET(0);
    __syncthreads();
    for (int t = 0; t < NT - 1; ++t) {
        LOADT(t + 1);
        COMPUTE(t & 1);
        WRITET((t + 1) & 1);
        __syncthreads();
    }
    COMPUTE((NT - 1) & 1);

    #pragma unroll
    for (int mt = 0; mt < 4; mt++)
        #pragma unroll
        for (int nt = 0; nt < 4; nt++)
            #pragma unroll
            for (int r = 0; r < 4; r++) {
                int row = m0 + wm + mt * 16 + q4 * 4 + r;
                int col = n0 + wn + nt * 16 + c;
                float v = acc[mt][nt][r];
                if (Ch) Ch[(size_t)row * N + col] = (f16)v;
                else    Cf[(size_t)row * N + col] = v + resid[(size_t)row * N + col];
            }
}

// ---------------- legacy GEMM: C[MxN] = A[MxK](f16) @ B[KxN](fp32) ----------------
__global__ __launch_bounds__(256) void gemm_f16_kernel(
    const f16* __restrict__ A, const float* __restrict__ B,
    f16* __restrict__ Ch, float* __restrict__ Cf, const float* __restrict__ resid,
    int N, int Kd)
{
    __shared__ f16 As[128 * 40];
    __shared__ f16 Bs[128 * 40];
    int tid = threadIdx.x;
    int m0 = blockIdx.y * 128, n0 = blockIdx.x * 128;
    int w = tid >> 6, lane = tid & 63, q4 = lane >> 4, c = lane & 15;
    int wm = (w >> 1) * 64, wn = (w & 1) * 64;
    f32x4 acc[4][4];
    #pragma unroll
    for (int i = 0; i < 4; i++)
        #pragma unroll
        for (int j = 0; j < 4; j++) acc[i][j] = (f32x4){0.f, 0.f, 0.f, 0.f};

    int ar = tid >> 1, aseg = (tid & 1) * 16;
    int bk = tid >> 3, bn = (tid & 7) * 16;

    for (int kb = 0; kb < Kd; kb += 32) {
        __syncthreads();
        {
            const uint4* g = (const uint4*)(A + (size_t)(m0 + ar) * Kd + kb + aseg);
            uint4 u0 = g[0], u1 = g[1];
            *(uint4*)&As[ar * 40 + aseg] = u0;
            *(uint4*)&As[ar * 40 + aseg + 8] = u1;
        }
        {
            const float* g = B + (size_t)(kb + bk) * N + n0 + bn;
            float4 f0 = *(const float4*)(g);
            float4 f1 = *(const float4*)(g + 4);
            float4 f2 = *(const float4*)(g + 8);
            float4 f3 = *(const float4*)(g + 12);
            float vv[16] = {f0.x, f0.y, f0.z, f0.w, f1.x, f1.y, f1.z, f1.w,
                            f2.x, f2.y, f2.z, f2.w, f3.x, f3.y, f3.z, f3.w};
            #pragma unroll
            for (int i = 0; i < 16; i++) Bs[(bn + i) * 40 + bk] = (f16)vv[i];
        }
        __syncthreads();
        half8 aF[4], bF[4];
        #pragma unroll
        for (int mt = 0; mt < 4; mt++)
            aF[mt] = *(const half8*)&As[(wm + mt * 16 + c) * 40 + q4 * 8];
        #pragma unroll
        for (int nt = 0; nt < 4; nt++)
            bF[nt] = *(const half8*)&Bs[(wn + nt * 16 + c) * 40 + q4 * 8];
        #pragma unroll
        for (int mt = 0; mt < 4; mt++)
            #pragma unroll
            for (int nt = 0; nt < 4; nt++)
                acc[mt][nt] = mfma16(aF[mt], bF[nt], acc[mt][nt]);
    }
    #pragma unroll
    for (int mt = 0; mt < 4; mt++)
        #pragma unroll
        for (int nt = 0; nt < 4; nt++)
            #pragma unroll
            for (int r = 0; r < 4; r++) {
                int row = m0 + wm + mt * 16 + q4 * 4 + r;
                int col = n0 + wn + nt * 16 + c;
                float v = acc[mt][nt][r];
                if (Ch) Ch[(size_t)row * N + col] = (f16)v;
                else    Cf[(size_t)row * N + col] = v + resid[(size_t)row * N + col];
            }
}

// ---------------- per-head QK RMSNorm + RoPE (in place, f16) ----------------
__global__ __launch_bounds__(64) void qknorm_rope_kernel(
    f16* __restrict__ qb, f16* __restrict__ kb,
    const float* __restrict__ qn, const float* __restrict__ kn,
    const float* __restrict__ cosp, const float* __restrict__ sinp)
{
    int t = blockIdx.x, y = blockIdx.y, lane = threadIdx.x;
    f16* ptr; const float* w;
    if (y < NHQ) { ptr = qb + (size_t)t * NHQ * HD + y * HD; w = qn; }
    else         { ptr = kb + (size_t)t * NHKV * HD + (y - NHQ) * HD; w = kn; }
    float v0 = (float)ptr[lane], v1 = (float)ptr[lane + 64];
    float ss = v0 * v0 + v1 * v1;
    #pragma unroll
    for (int o = 32; o > 0; o >>= 1) ss += __shfl_xor(ss, o);
    float sc = rsqrtf(ss / (float)HD + EPS);
    float n0 = v0 * sc * w[lane], n1 = v1 * sc * w[lane + 64];
    float c0 = cosp[t * HD + lane],     s0 = sinp[t * HD + lane];
    float c1 = cosp[t * HD + lane + 64], s1 = sinp[t * HD + lane + 64];
    ptr[lane]      = (f16)(n0 * c0 - n1 * s0);
    ptr[lane + 64] = (f16)(n1 * c1 + n0 * s1);
}

// ---------------- causal GQA flash attention ----------------
__global__ __launch_bounds__(256) void attn_kernel(
    const f16* __restrict__ qb, const f16* __restrict__ kbuf,
    const f16* __restrict__ vbuf, f16* __restrict__ ob)
{
    int qt = blockIdx.x, hq = blockIdx.y, kvh = hq >> 3;
    int q0 = qt * 64;
    int tid = threadIdx.x, w = tid >> 6, lane = tid & 63, q4 = lane >> 4, c = lane & 15;
    __shared__ f16 Qs[64 * 136];
    __shared__ f16 Ks[64 * 136];
    __shared__ f16 Vt[128 * 72];
    __shared__ f16 Ps[64 * 72];
    {
        int r = tid >> 2, seg = (tid & 3) * 32;
        const uint4* g = (const uint4*)(qb + (size_t)(q0 + r) * (NHQ * HD) + hq * HD + seg);
        uint4* d = (uint4*)&Qs[r * 136 + seg];
        d[0] = g[0]; d[1] = g[1]; d[2] = g[2]; d[3] = g[3];
    }
    float mi[4] = {-1e30f, -1e30f, -1e30f, -1e30f};
    float li[4] = {0.f, 0.f, 0.f, 0.f};
    f32x4 O[8];
    #pragma unroll
    for (int i = 0; i < 8; i++) O[i] = (f32x4){0.f, 0.f, 0.f, 0.f};
    const float scale = 0.08838834764831845f;

    for (int kt = 0; kt <= qt; kt++) {
        __syncthreads();
        {
            int r = tid >> 2, seg = (tid & 3) * 32;
            const uint4* g = (const uint4*)(kbuf + (size_t)(kt * 64 + r) * (NHKV * HD) + kvh * HD + seg);
            uint4* d = (uint4*)&Ks[r * 136 + seg];
            d[0] = g[0]; d[1] = g[1]; d[2] = g[2]; d[3] = g[3];
            const uint4* gv = (const uint4*)(vbuf + (size_t)(kt * 64 + r) * (NHKV * HD) + kvh * HD + seg);
            union { uint4 u; f16 h[8]; } t0, t1, t2, t3;
            t0.u = gv[0]; t1.u = gv[1]; t2.u = gv[2]; t3.u = gv[3];
            #pragma unroll
            for (int i = 0; i < 8; i++) {
                Vt[(seg + i) * 72 + r]      = t0.h[i];
                Vt[(seg + 8 + i) * 72 + r]  = t1.h[i];
                Vt[(seg + 16 + i) * 72 + r] = t2.h[i];
                Vt[(seg + 24 + i) * 72 + r] = t3.h[i];
            }
        }
        __syncthreads();
        f32x4 s[4];
        #pragma unroll
        for (int nt = 0; nt < 4; nt++) s[nt] = (f32x4){0.f, 0.f, 0.f, 0.f};
        #pragma unroll
        for (int kk = 0; kk < 4; kk++) {
            half8 a = *(const half8*)&Qs[(w * 16 + c) * 136 + kk * 32 + q4 * 8];
            #pragma unroll
            for (int nt = 0; nt < 4; nt++) {
                half8 b = *(const half8*)&Ks[(nt * 16 + c) * 136 + kk * 32 + q4 * 8];
                s[nt] = mfma16(a, b, s[nt]);
            }
        }
        bool diag = (kt == qt);
        float rmax[4] = {-1e30f, -1e30f, -1e30f, -1e30f};
        #pragma unroll
        for (int nt = 0; nt < 4; nt++)
            #pragma unroll
            for (int r = 0; r < 4; r++) {
                float v = s[nt][r] * scale;
                if (diag && (nt * 16 + c) > (w * 16 + q4 * 4 + r)) v = -1e30f;
                s[nt][r] = v;
                rmax[r] = fmaxf(rmax[r], v);
            }
        #pragma unroll
        for (int o = 1; o < 16; o <<= 1)
            #pragma unroll
            for (int r = 0; r < 4; r++) rmax[r] = fmaxf(rmax[r], __shfl_xor(rmax[r], o));
        float alpha[4];
        #pragma unroll
        for (int r = 0; r < 4; r++) {
            float mn = fmaxf(mi[r], rmax[r]);
            alpha[r] = expf(mi[r] - mn);
            mi[r] = mn;
        }
        float rs[4] = {0.f, 0.f, 0.f, 0.f};
        #pragma unroll
        for (int nt = 0; nt < 4; nt++)
            #pragma unroll
            for (int r = 0; r < 4; r++) {
                float p = expf(s[nt][r] - mi[r]);
                s[nt][r] = p;
                rs[r] += p;
            }
        #pragma unroll
        for (int o = 1; o < 16; o <<= 1)
            #pragma unroll
            for (int r = 0; r < 4; r++) rs[r] += __shfl_xor(rs[r], o);
        #pragma unroll
        for (int r = 0; r < 4; r++) li[r] = li[r] * alpha[r] + rs[r];
        #pragma unroll
        for (int nt = 0; nt < 8; nt++)
            #pragma unroll
            for (int r = 0; r < 4; r++) O[nt][r] *= alpha[r];
        #pragma unroll
        for (int nt = 0; nt < 4; nt++)
            #pragma unroll
            for (int r = 0; r < 4; r++)
                Ps[(w * 16 + q4 * 4 + r) * 72 + nt * 16 + c] = (f16)s[nt][r];
        __syncthreads();
        #pragma unroll
        for (int kk = 0; kk < 2; kk++) {
            half8 a = *(const half8*)&Ps[(w * 16 + c) * 72 + kk * 32 + q4 * 8];
            #pragma unroll
            for (int nt = 0; nt < 8; nt++) {
                half8 b = *(const half8*)&Vt[(nt * 16 + c) * 72 + kk * 32 + q4 * 8];
                O[nt] = mfma16(a, b, O[nt]);
            }
        }
    }
    #pragma unroll
    for (int r = 0; r < 4; r++) {
        float inv = 1.f / li[r];
        int row = q0 + w * 16 + q4 * 4 + r;
        #pragma unroll
        for (int nt = 0; nt < 8; nt++)
            ob[(size_t)row * (NHQ * HD) + hq * HD + nt * 16 + c] = (f16)(O[nt][r] * inv);
    }
}

// ---------------- gate ----------------
__global__ __launch_bounds__(256) void gate_kernel(
    const float* __restrict__ x2, const float* __restrict__ pw,
    const float* __restrict__ gw, float* __restrict__ topw,
    int* __restrict__ counts, int* __restrict__ bucket)
{
    int token = blockIdx.x, tid = threadIdx.x;
    const float* xr = x2 + (size_t)token * HID;
    float4 a = *(const float4*)(xr + tid * 8);
    float4 b = *(const float4*)(xr + tid * 8 + 4);
    float ss = a.x*a.x + a.y*a.y + a.z*a.z + a.w*a.w
             + b.x*b.x + b.y*b.y + b.z*b.z + b.w*b.w;
    __shared__ float red[4];
    __shared__ float lg[NEXP];
    #pragma unroll
    for (int o = 32; o > 0; o >>= 1) ss += __shfl_xor(ss, o);
    if ((tid & 63) == 0) red[tid >> 6] = ss;
    __syncthreads();
    float tot = red[0] + red[1] + red[2] + red[3];
    float inv = rsqrtf(tot / (float)HID + EPS);
    int e = tid >> 3, sub = tid & 7;
    const float* ge = gw + (size_t)e * HID;
    float acc = 0.f;
    for (int i = sub; i < HID; i += 8) acc += xr[i] * pw[i] * ge[i];
    acc *= inv;
    acc += __shfl_xor(acc, 1);
    acc += __shfl_xor(acc, 2);
    acc += __shfl_xor(acc, 4);
    if (sub == 0) lg[e] = acc;
    __syncthreads();
    if (tid == 0) {
        float m = lg[0];
        for (int i = 1; i < NEXP; i++) m = fmaxf(m, lg[i]);
        float ex[NEXP];
        for (int i = 0; i < NEXP; i++) ex[i] = expf(lg[i] - m);
        bool used[NEXP];
        for (int i = 0; i < NEXP; i++) used[i] = false;
        int ids[NTOP]; float vals[NTOP]; float sum4 = 0.f;
        for (int j = 0; j < NTOP; j++) {
            int best = -1; float bv = -1.f;
            for (int i = 0; i < NEXP; i++)
                if (!used[i] && ex[i] > bv) { bv = ex[i]; best = i; }
            used[best] = true; ids[j] = best; vals[j] = bv; sum4 += bv;
        }
        for (int j = 0; j < NTOP; j++) {
            topw[token * NTOP + j] = vals[j] / sum4;
            int pos = atomicAdd(&counts[ids[j]], 1);
            bucket[ids[j] * SEQ + pos] = token * NTOP + j;
        }
    }
}

// ---------------- MoE pass A (pipelined): act = silu(x@wg) * (x@wu) --------------
// 1-D grid (SEQ/64 * NEXP * NIMM/128), XCD-swizzled so blocks sharing an
// (expert, nb) weight panel land on the same XCD (L2 reuse).
__global__ __launch_bounds__(256) void moe_gu_t_kernel(
    const f16* __restrict__ h2, const f16* __restrict__ wgT,
    const f16* __restrict__ wuT, const int* __restrict__ counts,
    const int* __restrict__ bucket, f16* __restrict__ act)
{
    int id = blockIdx.x;
    int logical = (id & 7) * ((int)gridDim.x >> 3) + (id >> 3);
    int mt64 = logical & 31;
    int e = (logical >> 5) & 31;
    int nb = logical >> 10;
    int cnt = counts[e];
    if (mt64 * 64 >= cnt) return;
    __shared__ f16 As[2][64 * 40];
    __shared__ f16 Bg[2][128 * 40];
    __shared__ f16 Bu[2][128 * 40];
    __shared__ int pair_s[64];
    int tid = threadIdx.x;
    if (tid < 64) {
        int r = mt64 * 64 + tid;
        pair_s[tid] = (r < cnt) ? bucket[e * SEQ + r] : -1;
    }
    __syncthreads();
    int w = tid >> 6, lane = tid & 63, q4 = lane >> 4, c = lane & 15;
    f32x4 ag[4][2], au[4][2];
    #pragma unroll
    for (int m = 0; m < 4; m++)
        #pragma unroll
        for (int n = 0; n < 2; n++) {
            ag[m][n] = (f32x4){0.f, 0.f, 0.f, 0.f};
            au[m][n] = (f32x4){0.f, 0.f, 0.f, 0.f};
        }
    int ar = tid >> 2, aseg = (tid & 3) * 8;
    int br = tid >> 1, bseg = (tid & 1) * 16;
    int n0 = nb * 128;
    const f16* gBase = wgT + (size_t)e * NIMM * HID + (size_t)(n0 + br) * HID + bseg;
    const f16* uBase = wuT + (size_t)e * NIMM * HID + (size_t)(n0 + br) * HID + bseg;
    int pA = pair_s[ar];
    const f16* aBase = (pA >= 0) ? (h2 + (size_t)(pA >> 2) * HID + aseg) : nullptr;

    uint4 ra, rg0, rg1, ru0, ru1;
    auto LOADT = [&](int t) {
        int kb = t * 32;
        ra = (uint4){0u, 0u, 0u, 0u};
        if (aBase) ra = *(const uint4*)(aBase + kb);
        const uint4* gg = (const uint4*)(gBase + kb);
        rg0 = gg[0]; rg1 = gg[1];
        const uint4* gu = (const uint4*)(uBase + kb);
        ru0 = gu[0]; ru1 = gu[1];
    };
    auto WRITET = [&](int buf) {
        *(uint4*)&As[buf][ar * 40 + aseg]     = ra;
        *(uint4*)&Bg[buf][br * 40 + bseg]     = rg0;
        *(uint4*)&Bg[buf][br * 40 + bseg + 8] = rg1;
        *(uint4*)&Bu[buf][br * 40 + bseg]     = ru0;
        *(uint4*)&Bu[buf][br * 40 + bseg + 8] = ru1;
    };
    auto COMPUTE = [&](int buf) {
        half8 aF[4];
        #pragma unroll
        for (int m = 0; m < 4; m++)
            aF[m] = *(const half8*)&As[buf][(m * 16 + c) * 40 + q4 * 8];
        #pragma unroll
        for (int n = 0; n < 2; n++) {
            half8 bg = *(const half8*)&Bg[buf][(w * 32 + n * 16 + c) * 40 + q4 * 8];
            #pragma unroll
            for (int m = 0; m < 4; m++) ag[m][n] = mfma16(aF[m], bg, ag[m][n]);
            half8 bu = *(const half8*)&Bu[buf][(w * 32 + n * 16 + c) * 40 + q4 * 8];
            #pragma unroll
            for (int m = 0; m < 4; m++) au[m][n] = mfma16(aF[m], bu, au[m][n]);
        }
    };

    constexpr int NT = HID / 32;
    LOADT(0); WRITET(0);
    __syncthreads();
    for (int t = 0; t < NT - 1; ++t) {
        LOADT(t + 1);
        COMPUTE(t & 1);
        WRITET((t + 1) & 1);
        __syncthreads();
    }
    COMPUTE((NT - 1) & 1);

    #pragma unroll
    for (int n = 0; n < 2; n++)
        #pragma unroll
        for (int m = 0; m < 4; m++)
            #pragma unroll
            for (int r = 0; r < 4; r++) {
                int row = m * 16 + q4 * 4 + r;
                int p = pair_s[row];
                if (p >= 0) {
                    float g = ag[m][n][r], u = au[m][n][r];
                    float sv = g / (1.f + expf(-g)) * u;
                    act[(size_t)p * NIMM + n0 + w * 32 + n * 16 + c] = (f16)sv;
                }
            }
}

// ---------------- MoE pass B (pipelined): out += w * (act @ wd[e]) ---------------
__global__ __launch_bounds__(256) void moe_d_t_kernel(
    const f16* __restrict__ act, const f16* __restrict__ wdT,
    const int* __restrict__ counts, const int* __restrict__ bucket,
    const float* __restrict__ topw, float* __restrict__ out)
{
    int id = blockIdx.x;
    int logical = (id & 7) * ((int)gridDim.x >> 3) + (id >> 3);
    int mt64 = logical & 31;
    int e = (logical >> 5) & 31;
    int nb = logical >> 10;
    int cnt = counts[e];
    if (mt64 * 64 >= cnt) return;
    __shared__ f16 As[2][64 * 40];
    __shared__ f16 Bs[2][128 * 40];
    __shared__ int pair_s[64];
    int tid = threadIdx.x;
    if (tid < 64) {
        int r = mt64 * 64 + tid;
        pair_s[tid] = (r < cnt) ? bucket[e * SEQ + r] : -1;
    }
    __syncthreads();
    int w = tid >> 6, lane = tid & 63, q4 = lane >> 4, c = lane & 15;
    f32x4 acc[4][2];
    #pragma unroll
    for (int m = 0; m < 4; m++)
        #pragma unroll
        for (int n = 0; n < 2; n++) acc[m][n] = (f32x4){0.f, 0.f, 0.f, 0.f};
    int ar = tid >> 2, aseg = (tid & 3) * 8;
    int br = tid >> 1, bseg = (tid & 1) * 16;
    int n0 = nb * 128;
    const f16* Bbase = wdT + (size_t)e * HID * NIMM + (size_t)(n0 + br) * NIMM + bseg;
    int pA = pair_s[ar];
    const f16* aBase = (pA >= 0) ? (act + (size_t)pA * NIMM + aseg) : nullptr;

    uint4 ra, rb0, rb1;
    auto LOADT = [&](int t) {
        int kb = t * 32;
        ra = (uint4){0u, 0u, 0u, 0u};
        if (aBase) ra = *(const uint4*)(aBase + kb);
        const uint4* gb = (const uint4*)(Bbase + kb);
        rb0 = gb[0]; rb1 = gb[1];
    };
    auto WRITET = [&](int buf) {
        *(uint4*)&As[buf][ar * 40 + aseg]     = ra;
        *(uint4*)&Bs[buf][br * 40 + bseg]     = rb0;
        *(uint4*)&Bs[buf][br * 40 + bseg + 8] = rb1;
    };
    auto COMPUTE = [&](int buf) {
        half8 aF[4];
        #pragma unroll
        for (int m = 0; m < 4; m++)
            aF[m] = *(const half8*)&As[buf][(m * 16 + c) * 40 + q4 * 8];
        #pragma unroll
        for (int n = 0; n < 2; n++) {
            half8 b = *(const half8*)&Bs[buf][(w * 32 + n * 16 + c) * 40 + q4 * 8];
            #pragma unroll
            for (int m = 0; m < 4; m++) acc[m][n] = mfma16(aF[m], b, acc[m][n]);
        }
    };

    constexpr int NT = NIMM / 32;
    LOADT(0); WRITET(0);
    __syncthreads();
    for (int t = 0; t < NT - 1; ++t) {
        LOADT(t + 1);
        COMPUTE(t & 1);
        WRITET((t + 1) & 1);
        __syncthreads();
    }
    COMPUTE((NT - 1) & 1);

    #pragma unroll
    for (int n = 0; n < 2; n++)
        #pragma unroll
        for (int m = 0; m < 4; m++)
            #pragma unroll
            for (int r = 0; r < 4; r++) {
                int row = m * 16 + q4 * 4 + r;
                int p = pair_s[row];
                if (p >= 0) {
                    float wgt = topw[p];
                    atomicAdd(&out[(size_t)(p >> 2) * HID + n0 + w * 32 + n * 16 + c],
                              acc[m][n][r] * wgt);
                }
            }
}

// ---------------- legacy MoE kernels (fp32-weight fallback) ----------------
__global__ __launch_bounds__(256) void moe_gu_kernel(
    const f16* __restrict__ h2, const float* __restrict__ wg,
    const float* __restrict__ wu, const int* __restrict__ counts,
    const int* __restrict__ bucket, f16* __restrict__ act)
{
    int e = blockIdx.y, mt64 = blockIdx.x, nb = blockIdx.z;
    int cnt = counts[e];
    if (mt64 * 64 >= cnt) return;
    __shared__ f16 As[64 * 40];
    __shared__ f16 Bg[128 * 40];
    __shared__ f16 Bu[128 * 40];
    __shared__ int pair_s[64];
    int tid = threadIdx.x;
    if (tid < 64) {
        int r = mt64 * 64 + tid;
        pair_s[tid] = (r < cnt) ? bucket[e * SEQ + r] : -1;
    }
    __syncthreads();
    int w = tid >> 6, lane = tid & 63, q4 = lane >> 4, c = lane & 15;
    f32x4 ag[8], au[8];
    #pragma unroll
    for (int i = 0; i < 8; i++) { ag[i] = (f32x4){0.f,0.f,0.f,0.f}; au[i] = (f32x4){0.f,0.f,0.f,0.f}; }
    int ar = tid >> 2, aseg = (tid & 3) * 8;
    int bk = tid >> 3, bn = (tid & 7) * 16;
    const float* gB = wg + (size_t)e * HID * NIMM;
    const float* uB = wu + (size_t)e * HID * NIMM;
    int n0 = nb * 128;
    int pA = pair_s[ar];
    for (int kb = 0; kb < HID; kb += 32) {
        __syncthreads();
        {
            uint4 u = {0, 0, 0, 0};
            if (pA >= 0) u = *(const uint4*)(h2 + (size_t)(pA >> 2) * HID + kb + aseg);
            *(uint4*)&As[ar * 40 + aseg] = u;
        }
        {
            const float* g0 = gB + (size_t)(kb + bk) * NIMM + n0 + bn;
            float4 f0 = *(const float4*)(g0);
            float4 f1 = *(const float4*)(g0 + 4);
            float4 f2 = *(const float4*)(g0 + 8);
            float4 f3 = *(const float4*)(g0 + 12);
            float vv[16] = {f0.x, f0.y, f0.z, f0.w, f1.x, f1.y, f1.z, f1.w,
                            f2.x, f2.y, f2.z, f2.w, f3.x, f3.y, f3.z, f3.w};
            #pragma unroll
            for (int i = 0; i < 16; i++) Bg[(bn + i) * 40 + bk] = (f16)vv[i];
            const float* g1 = uB + (size_t)(kb + bk) * NIMM + n0 + bn;
            float4 u0 = *(const float4*)(g1);
            float4 u1 = *(const float4*)(g1 + 4);
            float4 u2 = *(const float4*)(g1 + 8);
            float4 u3 = *(const float4*)(g1 + 12);
            float uu[16] = {u0.x, u0.y, u0.z, u0.w, u1.x, u1.y, u1.z, u1.w,
                            u2.x, u2.y, u2.z, u2.w, u3.x, u3.y, u3.z, u3.w};
            #pragma unroll
            for (int i = 0; i < 16; i++) Bu[(bn + i) * 40 + bk] = (f16)uu[i];
        }
        __syncthreads();
        half8 aF = *(const half8*)&As[(w * 16 + c) * 40 + q4 * 8];
        #pragma unroll
        for (int nt = 0; nt < 8; nt++) {
            half8 bg = *(const half8*)&Bg[(nt * 16 + c) * 40 + q4 * 8];
            ag[nt] = mfma16(aF, bg, ag[nt]);
            half8 bu = *(const half8*)&Bu[(nt * 16 + c) * 40 + q4 * 8];
            au[nt] = mfma16(aF, bu, au[nt]);
        }
    }
    #pragma unroll
    for (int nt = 0; nt < 8; nt++)
        #pragma unroll
        for (int r = 0; r < 4; r++) {
            int rl = w * 16 + q4 * 4 + r;
            int p = pair_s[rl];
            if (p >= 0) {
                float g = ag[nt][r], u = au[nt][r];
                float sv = g / (1.f + expf(-g)) * u;
                act[(size_t)p * NIMM + n0 + nt * 16 + c] = (f16)sv;
            }
        }
}

__global__ __launch_bounds__(256) void moe_d_kernel(
    const f16* __restrict__ act, const float* __restrict__ wd,
    const int* __restrict__ counts, const int* __restrict__ bucket,
    const float* __restrict__ topw, float* __restrict__ out)
{
    int e = blockIdx.y, mt64 = blockIdx.x, nb = blockIdx.z;
    int cnt = counts[e];
    if (mt64 * 64 >= cnt) return;
    __shared__ f16 As[64 * 40];
    __shared__ f16 Bs[128 * 40];
    __shared__ int pair_s[64];
    int tid = threadIdx.x;
    if (tid < 64) {
        int r = mt64 * 64 + tid;
        pair_s[tid] = (r < cnt) ? bucket[e * SEQ + r] : -1;
    }
    __syncthreads();
    int w = tid >> 6, lane = tid & 63, q4 = lane >> 4, c = lane & 15;
    f32x4 acc[8];
    #pragma unroll
    for (int i = 0; i < 8; i++) acc[i] = (f32x4){0.f, 0.f, 0.f, 0.f};
    int ar = tid >> 2, aseg = (tid & 3) * 8;
    int bk = tid >> 3, bn = (tid & 7) * 16;
    const float* B = wd + (size_t)e * NIMM * HID;
    int n0 = nb * 128;
    int pA = pair_s[ar];
    for (int kb = 0; kb < NIMM; kb += 32) {
        __syncthreads();
        {
            uint4 u = {0, 0, 0, 0};
            if (pA >= 0) u = *(const uint4*)(act + (size_t)pA * NIMM + kb + aseg);
            *(uint4*)&As[ar * 40 + aseg] = u;
        }
        {
            const float* g = B + (size_t)(kb + bk) * HID + n0 + bn;
            float4 f0 = *(const float4*)(g);
            float4 f1 = *(const float4*)(g + 4);
            float4 f2 = *(const float4*)(g + 8);
            float4 f3 = *(const float4*)(g + 12);
            float vv[16] = {f0.x, f0.y, f0.z, f0.w, f1.x, f1.y, f1.z, f1.w,
                            f2.x, f2.y, f2.z, f2.w, f3.x, f3.y, f3.z, f3.w};
            #pragma unroll
            for (int i = 0; i < 16; i++) Bs[(bn + i) * 40 + bk] = (f16)vv[i];
        }
        __syncthreads();
        half8 aF = *(const half8*)&As[(w * 16 + c) * 40 + q4 * 8];
        #pragma unroll
        for (int nt = 0; nt < 8; nt++) {
            half8 b = *(const half8*)&Bs[(nt * 16 + c) * 40 + q4 * 8];
            acc[nt] = mfma16(aF, b, acc[nt]);
        }
    }
    #pragma unroll
    for (int nt = 0; nt < 8; nt++)
        #pragma unroll
        for (int r = 0; r < 4; r++) {
            int rl = w * 16 + q4 * 4 + r;
            int p = pair_s[rl];
            if (p >= 0) {
                float wgt = topw[p];
                atomicAdd(&out[(size_t)(p >> 2) * HID + n0 + nt * 16 + c],
                          acc[nt][r] * wgt);
            }
        }
}

// ---------------- launch ----------------
extern "C" void kernel_launch(void* const* d_in, const int* in_sizes, int n_in,
                              void* d_out, int out_size, void* d_ws, size_t ws_size,
                              hipStream_t stream)
{
    (void)in_sizes; (void)n_in; (void)out_size;
    const float* x       = (const float*)d_in[0];
    const float* cosp    = (const float*)d_in[1];
    const float* sinp    = (const float*)d_in[2];
    const float* in_ln   = (const float*)d_in[3];
    const float* post_ln = (const float*)d_in[4];
    const float* qn      = (const float*)d_in[5];
    const float* kn      = (const float*)d_in[6];
    const float* wq      = (const float*)d_in[7];
    const float* wk      = (const float*)d_in[8];
    const float* wv      = (const float*)d_in[9];
    const float* wo      = (const float*)d_in[10];
    const float* gw      = (const float*)d_in[11];
    const float* wg      = (const float*)d_in[12];
    const float* wu      = (const float*)d_in[13];
    const float* wd      = (const float*)d_in[14];
    float* out = (float*)d_out;

    char* ws = (char*)d_ws;
    auto alloc = [&](size_t bytes) { char* p = ws; ws += bytes; return p; };

    f16* h_h    = (f16*)alloc((size_t)SEQ * HID * 2);
    f16* q_h    = (f16*)alloc((size_t)SEQ * NHQ * HD * 2);
    f16* k_h    = (f16*)alloc((size_t)SEQ * NHKV * HD * 2);
    f16* v_h    = (f16*)alloc((size_t)SEQ * NHKV * HD * 2);
    f16* attn_h = (f16*)alloc((size_t)SEQ * NHQ * HD * 2);
    f16* h2_h   = (f16*)alloc((size_t)SEQ * HID * 2);
    f16* act    = (f16*)alloc((size_t)SEQ * NTOP * NIMM * 2);
    float* topw = (float*)alloc((size_t)SEQ * NTOP * 4);
    int* counts = (int*)alloc(128);
    int* bucket = (int*)alloc((size_t)NEXP * SEQ * 4);

    const size_t SZ_WQT = (size_t)(NHQ * HD) * HID * 2;
    const size_t SZ_WKT = (size_t)(NHKV * HD) * HID * 2;
    const size_t SZ_WOT = (size_t)HID * (NHQ * HD) * 2;
    const size_t SZ_WGT = (size_t)NEXP * NIMM * HID * 2;
    const size_t SZ_WDT = (size_t)NEXP * HID * NIMM * 2;
    size_t base_used = (size_t)(ws - (char*)d_ws);
    size_t need = base_used + SZ_WQT + 2 * SZ_WKT + SZ_WOT + 2 * SZ_WGT + SZ_WDT;
    bool fast = ws_size >= need;

    rmsnorm_f16_kernel<<<SEQ, 256, 0, stream>>>(x, in_ln, h_h);

    if (fast) {
        f16* wqT = (f16*)alloc(SZ_WQT);
        f16* wkT = (f16*)alloc(SZ_WKT);
        f16* wvT = (f16*)alloc(SZ_WKT);
        f16* woT = (f16*)alloc(SZ_WOT);
        f16* wgT = (f16*)alloc(SZ_WGT);
        f16* wuT = (f16*)alloc(SZ_WGT);
        f16* wdT = (f16*)alloc(SZ_WDT);

        transpose_f16_kernel<<<dim3(HID / 64, NHQ * HD / 64, 1), 256, 0, stream>>>(
            wq, wqT, HID, NHQ * HD);
        transpose_f16_kernel<<<dim3(HID / 64, NHKV * HD / 64, 1), 256, 0, stream>>>(
            wk, wkT, HID, NHKV * HD);
        transpose_f16_kernel<<<dim3(HID / 64, NHKV * HD / 64, 1), 256, 0, stream>>>(
            wv, wvT, HID, NHKV * HD);
        transpose_f16_kernel<<<dim3(NHQ * HD / 64, HID / 64, 1), 256, 0, stream>>>(
            wo, woT, NHQ * HD, HID);
        transpose_f16_kernel<<<dim3(HID / 64, NIMM / 64, NEXP), 256, 0, stream>>>(
            wg, wgT, HID, NIMM);
        transpose_f16_kernel<<<dim3(HID / 64, NIMM / 64, NEXP), 256, 0, stream>>>(
            wu, wuT, HID, NIMM);
        transpose_f16_kernel<<<dim3(NIMM / 64, HID / 64, NEXP), 256, 0, stream>>>(
            wd, wdT, NIMM, HID);

        gemm_f16t_kernel<<<dim3(NHQ * HD / 128, SEQ / 128), 256, 0, stream>>>(
            h_h, wqT, q_h, nullptr, nullptr, NHQ * HD, HID);
        gemm_f16t_kernel<<<dim3(NHKV * HD / 128, SEQ / 128), 256, 0, stream>>>(
            h_h, wkT, k_h, nullptr, nullptr, NHKV * HD, HID);
        gemm_f16t_kernel<<<dim3(NHKV * HD / 128, SEQ / 128), 256, 0, stream>>>(
            h_h, wvT, v_h, nullptr, nullptr, NHKV * HD, HID);
        qknorm_rope_kernel<<<dim3(SEQ, NHQ + NHKV), 64, 0, stream>>>(
            q_h, k_h, qn, kn, cosp, sinp);
        attn_kernel<<<dim3(SEQ / 64, NHQ), 256, 0, stream>>>(q_h, k_h, v_h, attn_h);
        gemm_f16t_kernel<<<dim3(HID / 128, SEQ / 128), 256, 0, stream>>>(
            attn_h, woT, nullptr, out, x, HID, NHQ * HD);
        rmsnorm_f16_kernel<<<SEQ, 256, 0, stream>>>(out, post_ln, h2_h);
        hipMemsetAsync(counts, 0, NEXP * sizeof(int), stream);
        gate_kernel<<<SEQ, 256, 0, stream>>>(out, post_ln, gw, topw, counts, bucket);
        moe_gu_t_kernel<<<dim3((SEQ / 64) * NEXP * (NIMM / 128)), 256, 0, stream>>>(
            h2_h, wgT, wuT, counts, bucket, act);
        moe_d_t_kernel<<<dim3((SEQ / 64) * NEXP * (HID / 128)), 256, 0, stream>>>(
            act, wdT, counts, bucket, topw, out);
    } else {
        gemm_f16_kernel<<<dim3(NHQ * HD / 128, SEQ / 128), 256, 0, stream>>>(
            h_h, wq, q_h, nullptr, nullptr, NHQ * HD, HID);
        gemm_f16_kernel<<<dim3(NHKV * HD / 128, SEQ / 128), 256, 0, stream>>>(
            h_h, wk, k_h, nullptr, nullptr, NHKV * HD, HID);
        gemm_f16_kernel<<<dim3(NHKV * HD / 128, SEQ / 128), 256, 0, stream>>>(
            h_h, wv, v_h, nullptr, nullptr, NHKV * HD, HID);
        qknorm_rope_kernel<<<dim3(SEQ, NHQ + NHKV), 64, 0, stream>>>(
            q_h, k_h, qn, kn, cosp, sinp);
        attn_kernel<<<dim3(SEQ / 64, NHQ), 256, 0, stream>>>(q_h, k_h, v_h, attn_h);
        gemm_f16_kernel<<<dim3(HID / 128, SEQ / 128), 256, 0, stream>>>(
            attn_h, wo, nullptr, out, x, HID, NHQ * HD);
        rmsnorm_f16_kernel<<<SEQ, 256, 0, stream>>>(out, post_ln, h2_h);
        hipMemsetAsync(counts, 0, NEXP * sizeof(int), stream);
        gate_kernel<<<SEQ, 256, 0, stream>>>(out, post_ln, gw, topw, counts, bucket);
        moe_gu_kernel<<<dim3(SEQ / 64, NEXP, NIMM / 128), 256, 0, stream>>>(
            h2_h, wg, wu, counts, bucket, act);
        moe_d_kernel<<<dim3(SEQ / 64, NEXP, HID / 128), 256, 0, stream>>>(
            act, wd, counts, bucket, topw, out);
    }
}